// Round 6
// baseline (355.612 us; speedup 1.0000x reference)
//
#include <hip/hip_runtime.h>

// ---------- types ----------
typedef short short8 __attribute__((ext_vector_type(8)));        // 8 bf16 MFMA A/B frag
typedef float floatx4 __attribute__((ext_vector_type(4)));       // MFMA C/D frag

__device__ __forceinline__ unsigned short f2bf(float f) {
    unsigned u = __float_as_uint(f);
    u += 0x7fffu + ((u >> 16) & 1u);   // RNE
    return (unsigned short)(u >> 16);
}
__device__ __forceinline__ float bf2f(unsigned short b) {
    unsigned u = (unsigned)b << 16;
    return __uint_as_float(u);
}

#define MFMA16(a, b, c)  __builtin_amdgcn_mfma_f32_16x16x32_bf16((a), (b), (c), 0, 0, 0)

// ---------- ws layout (bytes) ----------
static constexpr size_t Q_OFF    = 0;                    // q*QSCALE bf16 [8192][128] 2 MB
static constexpr size_t K_OFF    = 2u << 20;             // k bf16 [8192][128]        2 MB
static constexpr size_t U_OFF    = 4u << 20;             // u fp32 [8192]            32 KB
static constexpr size_t WFCT_OFF = U_OFF + 32768;        // W_fc^T bf16 [128][1024] 256 KB
static constexpr size_t WGT_OFF  = WFCT_OFF + 262144;    // W_gate^T bf16
static constexpr size_t WQT_OFF  = WGT_OFF + 262144;     // W_q^T bf16 [128][128] 32 KB
static constexpr size_t WKT_OFF  = WQT_OFF + 32768;      // W_k^T bf16
static constexpr size_t WVO_OFF  = WKT_OFF + 32768;      // wvo fp32 [128] + c0 fp32
static constexpr size_t LP_OFF   = 5u << 20;             // l partials fp32 [32][8192] 1 MB
static constexpr size_t OS_OFF   = 6u << 20;             // num partials fp32 [32][8192] 1 MB

static constexpr int NSPLIT = 32;
// log2(e)/sqrt(128): folded into stored q so P = exp2(S)
static constexpr float QSCALE = 0.1275174308f;

// ---------- K1: weight transposes + fp32->bf16 + wvo = W_v @ W_out GEMV ----------
__global__ void k_prep(const float* __restrict__ wfc, const float* __restrict__ wg,
                       const float* __restrict__ wq, const float* __restrict__ wk,
                       const float* __restrict__ wv, const float* __restrict__ wout,
                       const float* __restrict__ bv,
                       unsigned short* __restrict__ dfc, unsigned short* __restrict__ dg,
                       unsigned short* __restrict__ dq, unsigned short* __restrict__ dk,
                       float* __restrict__ wvo) {
    if (blockIdx.x == 1216) {
        int t = threadIdx.x;
        if (t < 128) {
            float s = 0.f;
            for (int j = 0; j < 128; ++j) s += wv[t * 128 + j] * wout[j];
            wvo[t] = s;
        } else if (t == 128) {
            float s = 0.f;
            for (int j = 0; j < 128; ++j) s += bv[j] * wout[j];
            wvo[128] = s;   // c0
        }
        return;
    }
    int i = blockIdx.x * 256 + threadIdx.x;
    const float* s; unsigned short* d; int K, base;
    if (i < 131072)      { s = wfc; d = dfc; K = 1024; base = 0; }
    else if (i < 262144) { s = wg;  d = dg;  K = 1024; base = 131072; }
    else if (i < 278528) { s = wq;  d = dq;  K = 128;  base = 262144; }
    else if (i < 294912) { s = wk;  d = dk;  K = 128;  base = 278528; }
    else return;
    int j = i - base;
    int kk = j >> 7, nn = j & 127;
    d[nn * K + kk] = f2bf(s[j]);
}

// ---------- K2: fused gated-linear + QK + u ----------
// grid 512 x 256 thr; block = 16 rows, 4 waves.
// Phase A: x fp32 staged->bf16 LDS (reg-prefetch dbuf, 1 barrier/kc); wave w -> 64 cols:
//   w<2 -> fc cols w*64, w>=2 -> gate cols (w-2)*64. mt=1, nt=4.
// Epilogue: gate->sigmoid LDS; fc -> h bf16 LDS.
// u[i] = h[i] @ wvo + c0 (per-thread 8-elem dot + 16-lane shfl reduce).
// Phase B: wave w -> 64 cols of [q|k]; q pre-scaled by QSCALE.
__global__ __launch_bounds__(256) void k_gq(const float* __restrict__ x,
                                            const unsigned short* __restrict__ wfct,
                                            const unsigned short* __restrict__ wgt,
                                            const float* __restrict__ bfc,
                                            const float* __restrict__ bg,
                                            const unsigned short* __restrict__ wqt,
                                            const unsigned short* __restrict__ wkt,
                                            const float* __restrict__ bq,
                                            const float* __restrict__ bk,
                                            const float* __restrict__ wvo,
                                            unsigned short* __restrict__ q,
                                            unsigned short* __restrict__ kt,
                                            float* __restrict__ ug) {
    __shared__ __align__(16) unsigned short xs[2][16 * 136];
    __shared__ __align__(16) float gbuf[16 * 132];
    __shared__ __align__(16) unsigned short hs[16 * 136];
    const int tid = threadIdx.x;
    const int i0 = blockIdx.x * 16;
    const int w = tid >> 6, lane = tid & 63;
    const int lr = lane & 15, lk = lane >> 4;

    const int isg = (w >= 2);
    const int ncol0 = (w & 1) * 64;
    const unsigned short* wt = isg ? wgt : wfct;

    floatx4 acc[4];
#pragma unroll
    for (int nt = 0; nt < 4; ++nt) acc[nt] = (floatx4)0.0f;

    const int srow = tid >> 4, se = tid & 15;   // 16 rows x 16 thr, 8 floats each
    const float* gp0 = x + (size_t)(i0 + srow) * 1024 + se * 8;
    float4 ra = *(const float4*)gp0;
    float4 rb = *(const float4*)(gp0 + 4);

    for (int kc = 0; kc < 8; ++kc) {
        {   // commit prefetched chunk to LDS buf kc&1 (fp32 -> bf16)
            short8 t;
            unsigned short* tp = (unsigned short*)&t;
            tp[0] = f2bf(ra.x); tp[1] = f2bf(ra.y); tp[2] = f2bf(ra.z); tp[3] = f2bf(ra.w);
            tp[4] = f2bf(rb.x); tp[5] = f2bf(rb.y); tp[6] = f2bf(rb.z); tp[7] = f2bf(rb.w);
            *(short8*)(xs[kc & 1] + srow * 136 + se * 8) = t;
        }
        if (kc < 7) {
            const float* gp = gp0 + (kc + 1) * 128;
            ra = *(const float4*)gp;
            rb = *(const float4*)(gp + 4);
        }
        __syncthreads();
        const unsigned short* xb = xs[kc & 1];
#pragma unroll
        for (int ks = 0; ks < 4; ++ks) {
            short8 a = *(const short8*)(xb + lr * 136 + ks * 32 + lk * 8);
#pragma unroll
            for (int nt = 0; nt < 4; ++nt) {
                short8 b = *(const short8*)(wt + (size_t)(ncol0 + nt * 16 + lr) * 1024 + kc * 128 + ks * 32 + lk * 8);
                acc[nt] = MFMA16(a, b, acc[nt]);
            }
        }
    }
    __syncthreads();
    // epilogue A: gate waves write sigmoid; fc waves combine -> h
    if (isg) {
#pragma unroll
        for (int nt = 0; nt < 4; ++nt) {
            int col = ncol0 + nt * 16 + lr;
            float bb = bg[col];
#pragma unroll
            for (int r = 0; r < 4; ++r) {
                float v = acc[nt][r] + bb;
                gbuf[(lk * 4 + r) * 132 + col] =
                    __builtin_amdgcn_rcpf(1.0f + __builtin_amdgcn_exp2f(-1.4426950408889634f * v));
            }
        }
    }
    __syncthreads();
    if (!isg) {
#pragma unroll
        for (int nt = 0; nt < 4; ++nt) {
            int col = ncol0 + nt * 16 + lr;
            float bb = bfc[col];
#pragma unroll
            for (int r = 0; r < 4; ++r) {
                int row = lk * 4 + r;
                hs[row * 136 + col] = f2bf((acc[nt][r] + bb) * gbuf[row * 132 + col]);
            }
        }
    }
    __syncthreads();

    // u[i] = h[i] @ wvo + c0 : thread t -> row t>>4, 8-elem chunk (t&15)*8
    {
        int row = tid >> 4, c = tid & 15;
        float s = 0.f;
#pragma unroll
        for (int e = 0; e < 8; ++e)
            s += bf2f(hs[row * 136 + c * 8 + e]) * wvo[c * 8 + e];
#pragma unroll
        for (int d = 1; d < 16; d <<= 1) s += __shfl_xor(s, d);
        if (c == 0) ug[i0 + row] = s + wvo[128];
    }

    // Phase B: q | k
    floatx4 qacc[4];
#pragma unroll
    for (int nt = 0; nt < 4; ++nt) qacc[nt] = (floatx4)0.0f;
    const unsigned short* wb = (w < 2) ? wqt : wkt;
    const int bcol0 = (w & 1) * 64;
#pragma unroll
    for (int ks = 0; ks < 4; ++ks) {
        short8 a = *(const short8*)(hs + lr * 136 + ks * 32 + lk * 8);
#pragma unroll
        for (int nt = 0; nt < 4; ++nt) {
            short8 b = *(const short8*)(wb + (size_t)(bcol0 + nt * 16 + lr) * 128 + ks * 32 + lk * 8);
            qacc[nt] = MFMA16(a, b, qacc[nt]);
        }
    }
    const float* bb_ = (w < 2) ? bq : bk;
    unsigned short* dst = (w < 2) ? q : kt;
    const float sc = (w < 2) ? QSCALE : 1.0f;
#pragma unroll
    for (int nt = 0; nt < 4; ++nt) {
        int col = bcol0 + nt * 16 + lr;
        float bb = bb_[col];
#pragma unroll
        for (int r = 0; r < 4; ++r)
            dst[(size_t)(i0 + lk * 4 + r) * 128 + col] = f2bf((qacc[nt][r] + bb) * sc);
    }
}

// ---------- K3: flash v6 — PV eliminated via u = V@W_out fold ----------
// grid (32, 32) x 256 thr; block = 256 q-rows, wave w owns m in [i0+w*64, +64).
// Per 64-j tile: stage K-tile + u-tile (reg-prefetch, 2 barriers); S^T = K@Q^T (MFMA);
// p = exp2(s): num += p*u_j, l += p (pure VALU, no P materialization, no PV MFMA).
__global__ __launch_bounds__(256, 4) void k_flash(const unsigned short* __restrict__ qg,
                                                  const unsigned short* __restrict__ kg,
                                                  const float* __restrict__ ug,
                                                  float* __restrict__ os,
                                                  float* __restrict__ lp) {
    __shared__ __align__(16) unsigned short Ks[64 * 136];
    __shared__ __align__(16) float Us[64];
    const int tid = threadIdx.x;
    const int i0 = blockIdx.x * 256;
    const int w = tid >> 6, lane = tid & 63;
    const int lr = lane & 15, lk = lane >> 4;

    // Q fragments (bf16, pre-scaled) in registers: rows i0 + w*64 .. +64
    short8 qf[4][4];
#pragma unroll
    for (int mt = 0; mt < 4; ++mt)
#pragma unroll
        for (int ks = 0; ks < 4; ++ks)
            qf[mt][ks] = *(const short8*)(qg + (size_t)(i0 + w * 64 + mt * 16 + lr) * 128 + ks * 32 + lk * 8);

    float numv[4] = {0.f, 0.f, 0.f, 0.f};
    float lsum[4] = {0.f, 0.f, 0.f, 0.f};

    const int jbase = blockIdx.y * 256;   // jrange = 8192/32
    const int krow = tid >> 2, kq = (tid & 3) << 5;   // 64 rows, 4 thr/row, 32 shorts each

    short8 pk4[4];
    float4 pu;
    {   // prefetch tile 0
        const unsigned short* gk = kg + (size_t)(jbase + krow) * 128 + kq;
#pragma unroll
        for (int i = 0; i < 4; ++i) pk4[i] = *(const short8*)(gk + i * 8);
        if (tid < 16) pu = *(const float4*)(ug + jbase + tid * 4);
    }

    for (int jt = 0; jt < 4; ++jt) {
        __syncthreads();                 // previous tile's reads done
        {   // commit prefetched tile
            unsigned short* dk = Ks + krow * 136 + kq;
#pragma unroll
            for (int i = 0; i < 4; ++i) *(short8*)(dk + i * 8) = pk4[i];
            if (tid < 16) *(float4*)(Us + tid * 4) = pu;
        }
        if (jt < 3) {                    // prefetch next tile
            int j0 = jbase + (jt + 1) * 64;
            const unsigned short* gk = kg + (size_t)(j0 + krow) * 128 + kq;
#pragma unroll
            for (int i = 0; i < 4; ++i) pk4[i] = *(const short8*)(gk + i * 8);
            if (tid < 16) pu = *(const float4*)(ug + j0 + tid * 4);
        }
        __syncthreads();                 // staging visible

#pragma unroll
        for (int j4 = 0; j4 < 4; ++j4) {
            floatx4 sacc[4];
#pragma unroll
            for (int mt = 0; mt < 4; ++mt) sacc[mt] = (floatx4)0.0f;
#pragma unroll
            for (int ks = 0; ks < 4; ++ks) {
                short8 af = *(const short8*)(Ks + (j4 * 16 + lr) * 136 + ks * 32 + lk * 8);
#pragma unroll
                for (int mt = 0; mt < 4; ++mt)
                    sacc[mt] = MFMA16(af, qf[mt][ks], sacc[mt]);
            }
            // p = exp2(s); num += p*u; l += p   (u broadcast-read from LDS)
            floatx4 uu = *(const floatx4*)(Us + j4 * 16 + lk * 4);
#pragma unroll
            for (int mt = 0; mt < 4; ++mt) {
#pragma unroll
                for (int r = 0; r < 4; ++r) {
                    float p = __builtin_amdgcn_exp2f(sacc[mt][r]);
                    numv[mt] += p * uu[r];
                    lsum[mt] += p;
                }
            }
        }
    }

    // reduce over lk (lane bits 4,5) and store per-split partials
#pragma unroll
    for (int mt = 0; mt < 4; ++mt) {
        float n = numv[mt], l = lsum[mt];
        n += __shfl_xor(n, 16); n += __shfl_xor(n, 32);
        l += __shfl_xor(l, 16); l += __shfl_xor(l, 32);
        if (lk == 0) {
            size_t idx = (size_t)blockIdx.y * 8192 + i0 + w * 64 + mt * 16 + lr;
            os[idx] = n;
            lp[idx] = l;
        }
    }
}

// ---------- K4: out[row] = (sum_s num_s) / (sum_s l_s) + b_out ----------
__global__ __launch_bounds__(256) void k_out(const float* __restrict__ os,
                                             const float* __restrict__ lp,
                                             const float* __restrict__ bout,
                                             float* __restrict__ out) {
    int row = blockIdx.x * 256 + threadIdx.x;
    float o = 0.f, l = 0.f;
    for (int s = 0; s < NSPLIT; ++s) {
        o += os[(size_t)s * 8192 + row];
        l += lp[(size_t)s * 8192 + row];
    }
    out[row] = o / l + bout[0];
}

// ---------- launch ----------
extern "C" void kernel_launch(void* const* d_in, const int* in_sizes, int n_in,
                              void* d_out, int out_size, void* d_ws, size_t ws_size,
                              hipStream_t stream) {
    const float* x    = (const float*)d_in[0];
    const float* Wfc  = (const float*)d_in[1];
    const float* bfc  = (const float*)d_in[2];
    const float* Wg   = (const float*)d_in[3];
    const float* bg   = (const float*)d_in[4];
    const float* Wq   = (const float*)d_in[5];
    const float* bq   = (const float*)d_in[6];
    const float* Wk   = (const float*)d_in[7];
    const float* bk   = (const float*)d_in[8];
    const float* Wv   = (const float*)d_in[9];
    const float* bv   = (const float*)d_in[10];
    const float* Wout = (const float*)d_in[11];
    const float* bout = (const float*)d_in[12];
    char* ws = (char*)d_ws;

    unsigned short* qb   = (unsigned short*)(ws + Q_OFF);
    unsigned short* kb   = (unsigned short*)(ws + K_OFF);
    float*          ub   = (float*)(ws + U_OFF);
    unsigned short* wfct = (unsigned short*)(ws + WFCT_OFF);
    unsigned short* wgt  = (unsigned short*)(ws + WGT_OFF);
    unsigned short* wqt  = (unsigned short*)(ws + WQT_OFF);
    unsigned short* wkt  = (unsigned short*)(ws + WKT_OFF);
    float*          wvo  = (float*)(ws + WVO_OFF);
    float* lpb = (float*)(ws + LP_OFF);
    float* osb = (float*)(ws + OS_OFF);

    k_prep<<<1217, 256, 0, stream>>>(Wfc, Wg, Wq, Wk, Wv, Wout, bv, wfct, wgt, wqt, wkt, wvo);
    k_gq<<<512, 256, 0, stream>>>(x, wfct, wgt, bfc, bg, wqt, wkt, bq, bk, wvo, qb, kb, ub);

    dim3 gf(32, NSPLIT);
    k_flash<<<gf, 256, 0, stream>>>(qb, kb, ub, osb, lpb);

    k_out<<<32, 256, 0, stream>>>(osb, lpb, bout, (float*)d_out);
}

// Round 7
// 173.191 us; speedup vs baseline: 2.0533x; 2.0533x over previous
//
#include <hip/hip_runtime.h>

// ---------- types ----------
typedef short short8 __attribute__((ext_vector_type(8)));        // 8 bf16 MFMA A/B frag
typedef float floatx4 __attribute__((ext_vector_type(4)));       // MFMA C/D frag

__device__ __forceinline__ unsigned short f2bf(float f) {
    unsigned u = __float_as_uint(f);
    u += 0x7fffu + ((u >> 16) & 1u);   // RNE
    return (unsigned short)(u >> 16);
}
__device__ __forceinline__ float bf2f(unsigned short b) {
    unsigned u = (unsigned)b << 16;
    return __uint_as_float(u);
}

#define MFMA16(a, b, c)  __builtin_amdgcn_mfma_f32_16x16x32_bf16((a), (b), (c), 0, 0, 0)

// ---------- ws layout (bytes) ----------
static constexpr size_t Q_OFF    = 0;                    // q*QSCALE bf16 [8192][128] 2 MB
static constexpr size_t K_OFF    = 2u << 20;             // k bf16 [8192][128]        2 MB
static constexpr size_t U_OFF    = 4u << 20;             // u fp32 [8192]            32 KB
static constexpr size_t WFCT_OFF = U_OFF + 32768;        // W_fc^T bf16 [128][1024] 256 KB
static constexpr size_t WGT_OFF  = WFCT_OFF + 262144;    // W_gate^T bf16
static constexpr size_t WQT_OFF  = WGT_OFF + 262144;     // W_q^T bf16 [128][128] 32 KB
static constexpr size_t WKT_OFF  = WQT_OFF + 32768;      // W_k^T bf16
static constexpr size_t WVO_OFF  = WKT_OFF + 32768;      // wvo fp32 [128] + c0 fp32
static constexpr size_t LP_OFF   = 5u << 20;             // l partials fp32 [32][8192] 1 MB
static constexpr size_t OS_OFF   = 6u << 20;             // num partials fp32 [32][8192] 1 MB

static constexpr int NSPLIT = 32;
// log2(e)/sqrt(128): folded into stored q so P = exp2(S)
static constexpr float QSCALE = 0.1275174308f;

// ---------- K1: weight transposes + fp32->bf16 + wvo = W_v @ W_out GEMV ----------
__global__ void k_prep(const float* __restrict__ wfc, const float* __restrict__ wg,
                       const float* __restrict__ wq, const float* __restrict__ wk,
                       const float* __restrict__ wv, const float* __restrict__ wout,
                       const float* __restrict__ bv,
                       unsigned short* __restrict__ dfc, unsigned short* __restrict__ dg,
                       unsigned short* __restrict__ dq, unsigned short* __restrict__ dk,
                       float* __restrict__ wvo) {
    if (blockIdx.x == 1216) {
        int t = threadIdx.x;
        if (t < 128) {
            float s = 0.f;
            for (int j = 0; j < 128; ++j) s += wv[t * 128 + j] * wout[j];
            wvo[t] = s;
        } else if (t == 128) {
            float s = 0.f;
            for (int j = 0; j < 128; ++j) s += bv[j] * wout[j];
            wvo[128] = s;   // c0
        }
        return;
    }
    int i = blockIdx.x * 256 + threadIdx.x;
    const float* s; unsigned short* d; int K, base;
    if (i < 131072)      { s = wfc; d = dfc; K = 1024; base = 0; }
    else if (i < 262144) { s = wg;  d = dg;  K = 1024; base = 131072; }
    else if (i < 278528) { s = wq;  d = dq;  K = 128;  base = 262144; }
    else if (i < 294912) { s = wk;  d = dk;  K = 128;  base = 278528; }
    else return;
    int j = i - base;
    int kk = j >> 7, nn = j & 127;
    d[nn * K + kk] = f2bf(s[j]);
}

// ---------- K2: fused gated-linear + QK + u ----------
// grid 512 x 256 thr; block = 16 rows, 4 waves.
__global__ __launch_bounds__(256) void k_gq(const float* __restrict__ x,
                                            const unsigned short* __restrict__ wfct,
                                            const unsigned short* __restrict__ wgt,
                                            const float* __restrict__ bfc,
                                            const float* __restrict__ bg,
                                            const unsigned short* __restrict__ wqt,
                                            const unsigned short* __restrict__ wkt,
                                            const float* __restrict__ bq,
                                            const float* __restrict__ bk,
                                            const float* __restrict__ wvo,
                                            unsigned short* __restrict__ q,
                                            unsigned short* __restrict__ kt,
                                            float* __restrict__ ug) {
    __shared__ __align__(16) unsigned short xs[2][16 * 136];
    __shared__ __align__(16) float gbuf[16 * 132];
    __shared__ __align__(16) unsigned short hs[16 * 136];
    const int tid = threadIdx.x;
    const int i0 = blockIdx.x * 16;
    const int w = tid >> 6, lane = tid & 63;
    const int lr = lane & 15, lk = lane >> 4;

    const int isg = (w >= 2);
    const int ncol0 = (w & 1) * 64;
    const unsigned short* wt = isg ? wgt : wfct;

    floatx4 acc[4];
#pragma unroll
    for (int nt = 0; nt < 4; ++nt) acc[nt] = (floatx4)0.0f;

    const int srow = tid >> 4, se = tid & 15;   // 16 rows x 16 thr, 8 floats each
    const float* gp0 = x + (size_t)(i0 + srow) * 1024 + se * 8;
    float4 ra = *(const float4*)gp0;
    float4 rb = *(const float4*)(gp0 + 4);

    for (int kc = 0; kc < 8; ++kc) {
        {   // commit prefetched chunk to LDS buf kc&1 (fp32 -> bf16)
            short8 t;
            unsigned short* tp = (unsigned short*)&t;
            tp[0] = f2bf(ra.x); tp[1] = f2bf(ra.y); tp[2] = f2bf(ra.z); tp[3] = f2bf(ra.w);
            tp[4] = f2bf(rb.x); tp[5] = f2bf(rb.y); tp[6] = f2bf(rb.z); tp[7] = f2bf(rb.w);
            *(short8*)(xs[kc & 1] + srow * 136 + se * 8) = t;
        }
        if (kc < 7) {
            const float* gp = gp0 + (kc + 1) * 128;
            ra = *(const float4*)gp;
            rb = *(const float4*)(gp + 4);
        }
        __syncthreads();
        const unsigned short* xb = xs[kc & 1];
#pragma unroll
        for (int ks = 0; ks < 4; ++ks) {
            short8 a = *(const short8*)(xb + lr * 136 + ks * 32 + lk * 8);
#pragma unroll
            for (int nt = 0; nt < 4; ++nt) {
                short8 b = *(const short8*)(wt + (size_t)(ncol0 + nt * 16 + lr) * 1024 + kc * 128 + ks * 32 + lk * 8);
                acc[nt] = MFMA16(a, b, acc[nt]);
            }
        }
    }
    __syncthreads();
    // epilogue A: gate waves write sigmoid; fc waves combine -> h
    if (isg) {
#pragma unroll
        for (int nt = 0; nt < 4; ++nt) {
            int col = ncol0 + nt * 16 + lr;
            float bb = bg[col];
#pragma unroll
            for (int r = 0; r < 4; ++r) {
                float v = acc[nt][r] + bb;
                gbuf[(lk * 4 + r) * 132 + col] =
                    __builtin_amdgcn_rcpf(1.0f + __builtin_amdgcn_exp2f(-1.4426950408889634f * v));
            }
        }
    }
    __syncthreads();
    if (!isg) {
#pragma unroll
        for (int nt = 0; nt < 4; ++nt) {
            int col = ncol0 + nt * 16 + lr;
            float bb = bfc[col];
#pragma unroll
            for (int r = 0; r < 4; ++r) {
                int row = lk * 4 + r;
                hs[row * 136 + col] = f2bf((acc[nt][r] + bb) * gbuf[row * 132 + col]);
            }
        }
    }
    __syncthreads();

    // u[i] = h[i] @ wvo + c0 : thread t -> row t>>4, 8-elem chunk (t&15)*8
    {
        int row = tid >> 4, c = tid & 15;
        float s = 0.f;
#pragma unroll
        for (int e = 0; e < 8; ++e)
            s += bf2f(hs[row * 136 + c * 8 + e]) * wvo[c * 8 + e];
#pragma unroll
        for (int d = 1; d < 16; d <<= 1) s += __shfl_xor(s, d);
        if (c == 0) ug[i0 + row] = s + wvo[128];
    }

    // Phase B: q | k
    floatx4 qacc[4];
#pragma unroll
    for (int nt = 0; nt < 4; ++nt) qacc[nt] = (floatx4)0.0f;
    const unsigned short* wb = (w < 2) ? wqt : wkt;
    const int bcol0 = (w & 1) * 64;
#pragma unroll
    for (int ks = 0; ks < 4; ++ks) {
        short8 a = *(const short8*)(hs + lr * 136 + ks * 32 + lk * 8);
#pragma unroll
        for (int nt = 0; nt < 4; ++nt) {
            short8 b = *(const short8*)(wb + (size_t)(bcol0 + nt * 16 + lr) * 128 + ks * 32 + lk * 8);
            qacc[nt] = MFMA16(a, b, qacc[nt]);
        }
    }
    const float* bb_ = (w < 2) ? bq : bk;
    unsigned short* dst = (w < 2) ? q : kt;
    const float sc = (w < 2) ? QSCALE : 1.0f;
#pragma unroll
    for (int nt = 0; nt < 4; ++nt) {
        int col = bcol0 + nt * 16 + lr;
        float bb = bb_[col];
#pragma unroll
        for (int r = 0; r < 4; ++r)
            dst[(size_t)(i0 + lk * 4 + r) * 128 + col] = f2bf((qacc[nt][r] + bb) * sc);
    }
}

// ---------- K3: flash v6 — PV eliminated via u = V@W_out fold ----------
// grid (32, 32) x 256 thr; block = 256 q-rows, wave w owns m in [i0+w*64, +64).
// Per 64-j tile: stage K-tile + u-tile (reg-prefetch, 2 barriers); S^T = K@Q^T (MFMA);
// p = exp2(s): num += p*u_j, l += p (pure VALU, no P materialization, no PV MFMA).
// launch_bounds(256,1): ~150 VGPR needed — do NOT cap below (r6: cap 128 -> spill storm).
__global__ __launch_bounds__(256, 1) void k_flash(const unsigned short* __restrict__ qg,
                                                  const unsigned short* __restrict__ kg,
                                                  const float* __restrict__ ug,
                                                  float* __restrict__ os,
                                                  float* __restrict__ lp) {
    __shared__ __align__(16) unsigned short Ks[64 * 136];
    __shared__ __align__(16) float Us[64];
    const int tid = threadIdx.x;
    const int i0 = blockIdx.x * 256;
    const int w = tid >> 6, lane = tid & 63;
    const int lr = lane & 15, lk = lane >> 4;

    // Q fragments (bf16, pre-scaled) in registers: rows i0 + w*64 .. +64
    short8 qf[4][4];
#pragma unroll
    for (int mt = 0; mt < 4; ++mt)
#pragma unroll
        for (int ks = 0; ks < 4; ++ks)
            qf[mt][ks] = *(const short8*)(qg + (size_t)(i0 + w * 64 + mt * 16 + lr) * 128 + ks * 32 + lk * 8);

    float numv[4] = {0.f, 0.f, 0.f, 0.f};
    float lsum[4] = {0.f, 0.f, 0.f, 0.f};

    const int jbase = blockIdx.y * 256;   // jrange = 8192/32
    const int krow = tid >> 2, kq = (tid & 3) << 5;   // 64 rows, 4 thr/row, 32 shorts each

    short8 pk4[4];
    float4 pu;
    {   // prefetch tile 0
        const unsigned short* gk = kg + (size_t)(jbase + krow) * 128 + kq;
#pragma unroll
        for (int i = 0; i < 4; ++i) pk4[i] = *(const short8*)(gk + i * 8);
        if (tid < 16) pu = *(const float4*)(ug + jbase + tid * 4);
    }

    for (int jt = 0; jt < 4; ++jt) {
        __syncthreads();                 // previous tile's reads done
        {   // commit prefetched tile
            unsigned short* dk = Ks + krow * 136 + kq;
#pragma unroll
            for (int i = 0; i < 4; ++i) *(short8*)(dk + i * 8) = pk4[i];
            if (tid < 16) *(float4*)(Us + tid * 4) = pu;
        }
        if (jt < 3) {                    // prefetch next tile
            int j0 = jbase + (jt + 1) * 64;
            const unsigned short* gk = kg + (size_t)(j0 + krow) * 128 + kq;
#pragma unroll
            for (int i = 0; i < 4; ++i) pk4[i] = *(const short8*)(gk + i * 8);
            if (tid < 16) pu = *(const float4*)(ug + j0 + tid * 4);
        }
        __syncthreads();                 // staging visible

#pragma unroll
        for (int j4 = 0; j4 < 4; ++j4) {
            floatx4 sacc[4];
#pragma unroll
            for (int mt = 0; mt < 4; ++mt) sacc[mt] = (floatx4)0.0f;
#pragma unroll
            for (int ks = 0; ks < 4; ++ks) {
                short8 af = *(const short8*)(Ks + (j4 * 16 + lr) * 136 + ks * 32 + lk * 8);
#pragma unroll
                for (int mt = 0; mt < 4; ++mt)
                    sacc[mt] = MFMA16(af, qf[mt][ks], sacc[mt]);
            }
            // p = exp2(s); num += p*u; l += p   (u broadcast-read from LDS)
            floatx4 uu = *(const floatx4*)(Us + j4 * 16 + lk * 4);
#pragma unroll
            for (int mt = 0; mt < 4; ++mt) {
#pragma unroll
                for (int r = 0; r < 4; ++r) {
                    float p = __builtin_amdgcn_exp2f(sacc[mt][r]);
                    numv[mt] += p * uu[r];
                    lsum[mt] += p;
                }
            }
        }
    }

    // reduce over lk (lane bits 4,5) and store per-split partials
#pragma unroll
    for (int mt = 0; mt < 4; ++mt) {
        float n = numv[mt], l = lsum[mt];
        n += __shfl_xor(n, 16); n += __shfl_xor(n, 32);
        l += __shfl_xor(l, 16); l += __shfl_xor(l, 32);
        if (lk == 0) {
            size_t idx = (size_t)blockIdx.y * 8192 + i0 + w * 64 + mt * 16 + lr;
            os[idx] = n;
            lp[idx] = l;
        }
    }
}

// ---------- K4: out[row] = (sum_s num_s) / (sum_s l_s) + b_out ----------
__global__ __launch_bounds__(256) void k_out(const float* __restrict__ os,
                                             const float* __restrict__ lp,
                                             const float* __restrict__ bout,
                                             float* __restrict__ out) {
    int row = blockIdx.x * 256 + threadIdx.x;
    float o = 0.f, l = 0.f;
    for (int s = 0; s < NSPLIT; ++s) {
        o += os[(size_t)s * 8192 + row];
        l += lp[(size_t)s * 8192 + row];
    }
    out[row] = o / l + bout[0];
}

// ---------- launch ----------
extern "C" void kernel_launch(void* const* d_in, const int* in_sizes, int n_in,
                              void* d_out, int out_size, void* d_ws, size_t ws_size,
                              hipStream_t stream) {
    const float* x    = (const float*)d_in[0];
    const float* Wfc  = (const float*)d_in[1];
    const float* bfc  = (const float*)d_in[2];
    const float* Wg   = (const float*)d_in[3];
    const float* bg   = (const float*)d_in[4];
    const float* Wq   = (const float*)d_in[5];
    const float* bq   = (const float*)d_in[6];
    const float* Wk   = (const float*)d_in[7];
    const float* bk   = (const float*)d_in[8];
    const float* Wv   = (const float*)d_in[9];
    const float* bv   = (const float*)d_in[10];
    const float* Wout = (const float*)d_in[11];
    const float* bout = (const float*)d_in[12];
    char* ws = (char*)d_ws;

    unsigned short* qb   = (unsigned short*)(ws + Q_OFF);
    unsigned short* kb   = (unsigned short*)(ws + K_OFF);
    float*          ub   = (float*)(ws + U_OFF);
    unsigned short* wfct = (unsigned short*)(ws + WFCT_OFF);
    unsigned short* wgt  = (unsigned short*)(ws + WGT_OFF);
    unsigned short* wqt  = (unsigned short*)(ws + WQT_OFF);
    unsigned short* wkt  = (unsigned short*)(ws + WKT_OFF);
    float*          wvo  = (float*)(ws + WVO_OFF);
    float* lpb = (float*)(ws + LP_OFF);
    float* osb = (float*)(ws + OS_OFF);

    k_prep<<<1217, 256, 0, stream>>>(Wfc, Wg, Wq, Wk, Wv, Wout, bv, wfct, wgt, wqt, wkt, wvo);
    k_gq<<<512, 256, 0, stream>>>(x, wfct, wgt, bfc, bg, wqt, wkt, bq, bk, wvo, qb, kb, ub);

    dim3 gf(32, NSPLIT);
    k_flash<<<gf, 256, 0, stream>>>(qb, kb, ub, osb, lpb);

    k_out<<<32, 256, 0, stream>>>(osb, lpb, bout, (float*)d_out);
}

// Round 8
// 150.231 us; speedup vs baseline: 2.3671x; 1.1528x over previous
//
#include <hip/hip_runtime.h>

// ---------- types ----------
typedef short short8 __attribute__((ext_vector_type(8)));        // 8 bf16 MFMA A/B frag
typedef float floatx4 __attribute__((ext_vector_type(4)));       // MFMA C/D frag

__device__ __forceinline__ unsigned short f2bf(float f) {
    unsigned u = __float_as_uint(f);
    u += 0x7fffu + ((u >> 16) & 1u);   // RNE
    return (unsigned short)(u >> 16);
}
__device__ __forceinline__ float bf2f(unsigned short b) {
    unsigned u = (unsigned)b << 16;
    return __uint_as_float(u);
}

#define MFMA16(a, b, c)  __builtin_amdgcn_mfma_f32_16x16x32_bf16((a), (b), (c), 0, 0, 0)

// ---------- ws layout (bytes) ----------
static constexpr size_t Q_OFF    = 0;                    // q*QSCALE bf16 [8192][128] 2 MB
static constexpr size_t K_OFF    = 2u << 20;             // k bf16 [8192][128]        2 MB
static constexpr size_t U_OFF    = 4u << 20;             // u fp32 [8192]            32 KB
static constexpr size_t WFCT_OFF = U_OFF + 32768;        // W_fc packed bf16 256 KB
static constexpr size_t WGT_OFF  = WFCT_OFF + 262144;    // W_gate packed bf16
static constexpr size_t WQT_OFF  = WGT_OFF + 262144;     // W_q packed bf16 32 KB
static constexpr size_t WKT_OFF  = WQT_OFF + 32768;      // W_k packed bf16
static constexpr size_t WVO_OFF  = WKT_OFF + 32768;      // wvo fp32 [128] + c0 fp32
static constexpr size_t LP_OFF   = 5u << 20;             // l partials fp32 [32][8192] 1 MB
static constexpr size_t OS_OFF   = 6u << 20;             // num partials fp32 [32][8192] 1 MB

static constexpr int NSPLIT = 32;
// log2(e)/sqrt(128): folded into stored q so P = exp2(S)
static constexpr float QSCALE = 0.1275174308f;

// ---------- K1: weights -> MFMA-packed bf16 + wvo = W_v @ W_out GEMV ----------
// Packed layout: frag for (col-tile t, k-chunk c) is 64 lanes x 8 bf16 CONTIGUOUS:
//   idx = ((t*nchunk + c)*64 + (col%16) + 16*((k%32)/8))*8 + (k%8)
// so a wave's B-frag load is one coalesced 1 KB transaction (was a 16-txn gather).
__global__ void k_prep(const float* __restrict__ wfc, const float* __restrict__ wg,
                       const float* __restrict__ wq, const float* __restrict__ wk,
                       const float* __restrict__ wv, const float* __restrict__ wout,
                       const float* __restrict__ bv,
                       unsigned short* __restrict__ dfc, unsigned short* __restrict__ dg,
                       unsigned short* __restrict__ dq, unsigned short* __restrict__ dk,
                       float* __restrict__ wvo) {
    if (blockIdx.x == 1216) {
        int t = threadIdx.x;
        if (t < 128) {
            float s = 0.f;
            for (int j = 0; j < 128; ++j) s += wv[t * 128 + j] * wout[j];
            wvo[t] = s;
        } else if (t == 128) {
            float s = 0.f;
            for (int j = 0; j < 128; ++j) s += bv[j] * wout[j];
            wvo[128] = s;   // c0
        }
        return;
    }
    int i = blockIdx.x * 256 + threadIdx.x;
    const float* s; unsigned short* d; int base, nchunk;
    if (i < 131072)      { s = wfc; d = dfc; nchunk = 32; base = 0; }
    else if (i < 262144) { s = wg;  d = dg;  nchunk = 32; base = 131072; }
    else if (i < 278528) { s = wq;  d = dq;  nchunk = 4;  base = 262144; }
    else if (i < 294912) { s = wk;  d = dk;  nchunk = 4;  base = 278528; }
    else return;
    int j = i - base;
    int kk = j >> 7, nn = j & 127;        // source W[kk][nn], row-major K x 128
    int t = nn >> 4, lr = nn & 15;
    int c = kk >> 5, lk = (kk >> 3) & 3, e = kk & 7;
    d[(((t * nchunk + c) * 64) + lr + 16 * lk) * 8 + e] = f2bf(s[j]);
}

// ---------- K2: fused gated-linear + QK + u (packed-B) ----------
// grid 256 x 512 thr; block = 32 rows, 8 waves.
// Phase A: x fp32 -> bf16 LDS (reg-prefetch dbuf); wave w: w<4 fc cols (w&3)*32, w>=4 gate.
//   B-frags: single coalesced 1KB loads from packed weights.
// Epilogue: gate->sigmoid LDS; fc -> h bf16 LDS. u = h @ wvo + c0.
// Phase B: wave w: w<4 -> q cols (w&3)*32, w>=4 -> k; q pre-scaled by QSCALE.
__global__ __launch_bounds__(512) void k_gq(const float* __restrict__ x,
                                            const unsigned short* __restrict__ wfcp,
                                            const unsigned short* __restrict__ wgp,
                                            const float* __restrict__ bfc,
                                            const float* __restrict__ bg,
                                            const unsigned short* __restrict__ wqp,
                                            const unsigned short* __restrict__ wkp,
                                            const float* __restrict__ bq,
                                            const float* __restrict__ bk,
                                            const float* __restrict__ wvo,
                                            unsigned short* __restrict__ q,
                                            unsigned short* __restrict__ kt,
                                            float* __restrict__ ug) {
    __shared__ __align__(16) unsigned short xs[2][32 * 136];
    __shared__ __align__(16) float gbuf[32 * 132];
    __shared__ __align__(16) unsigned short hs[32 * 136];
    const int tid = threadIdx.x;
    const int i0 = blockIdx.x * 32;
    const int w = tid >> 6, lane = tid & 63;
    const int lr = lane & 15, lk = lane >> 4;

    const int isg = (w >= 4);
    const int wq4 = w & 3;                 // 0..3: which 32-col group
    const unsigned short* wp = isg ? wgp : wfcp;

    floatx4 acc[2][2];
#pragma unroll
    for (int mt = 0; mt < 2; ++mt)
#pragma unroll
        for (int nt = 0; nt < 2; ++nt) acc[mt][nt] = (floatx4)0.0f;

    const int srow = tid >> 4, se = tid & 15;   // 32 rows x 16 thr, 8 floats each
    const float* gp0 = x + (size_t)(i0 + srow) * 1024 + se * 8;
    float4 ra = *(const float4*)gp0;
    float4 rb = *(const float4*)(gp0 + 4);

    for (int kc = 0; kc < 8; ++kc) {
        {   // commit prefetched chunk to LDS buf kc&1 (fp32 -> bf16)
            short8 t;
            unsigned short* tp = (unsigned short*)&t;
            tp[0] = f2bf(ra.x); tp[1] = f2bf(ra.y); tp[2] = f2bf(ra.z); tp[3] = f2bf(ra.w);
            tp[4] = f2bf(rb.x); tp[5] = f2bf(rb.y); tp[6] = f2bf(rb.z); tp[7] = f2bf(rb.w);
            *(short8*)(xs[kc & 1] + srow * 136 + se * 8) = t;
        }
        if (kc < 7) {
            const float* gp = gp0 + (kc + 1) * 128;
            ra = *(const float4*)gp;
            rb = *(const float4*)(gp + 4);
        }
        __syncthreads();
        const unsigned short* xb = xs[kc & 1];
#pragma unroll
        for (int ks = 0; ks < 4; ++ks) {
            const int c = kc * 4 + ks;
            short8 a[2], b[2];
#pragma unroll
            for (int mt = 0; mt < 2; ++mt)
                a[mt] = *(const short8*)(xb + (mt * 16 + lr) * 136 + ks * 32 + lk * 8);
#pragma unroll
            for (int nt = 0; nt < 2; ++nt)
                b[nt] = *(const short8*)(wp + ((((size_t)(wq4 * 2 + nt)) * 32 + c) * 64 + lane) * 8);
#pragma unroll
            for (int mt = 0; mt < 2; ++mt)
#pragma unroll
                for (int nt = 0; nt < 2; ++nt)
                    acc[mt][nt] = MFMA16(a[mt], b[nt], acc[mt][nt]);
        }
    }
    __syncthreads();
    // epilogue A: gate waves write sigmoid; fc waves combine -> h
    if (isg) {
#pragma unroll
        for (int mt = 0; mt < 2; ++mt)
#pragma unroll
            for (int nt = 0; nt < 2; ++nt) {
                int col = wq4 * 32 + nt * 16 + lr;
                float bb = bg[col];
#pragma unroll
                for (int r = 0; r < 4; ++r) {
                    float v = acc[mt][nt][r] + bb;
                    gbuf[(mt * 16 + lk * 4 + r) * 132 + col] =
                        __builtin_amdgcn_rcpf(1.0f + __builtin_amdgcn_exp2f(-1.4426950408889634f * v));
                }
            }
    }
    __syncthreads();
    if (!isg) {
#pragma unroll
        for (int mt = 0; mt < 2; ++mt)
#pragma unroll
            for (int nt = 0; nt < 2; ++nt) {
                int col = wq4 * 32 + nt * 16 + lr;
                float bb = bfc[col];
#pragma unroll
                for (int r = 0; r < 4; ++r) {
                    int row = mt * 16 + lk * 4 + r;
                    hs[row * 136 + col] = f2bf((acc[mt][nt][r] + bb) * gbuf[row * 132 + col]);
                }
            }
    }
    __syncthreads();

    // u[i] = h[i] @ wvo + c0 : thread t -> row t>>4, 8-elem chunk (t&15)*8
    {
        int row = tid >> 4, c = tid & 15;
        float s = 0.f;
#pragma unroll
        for (int e = 0; e < 8; ++e)
            s += bf2f(hs[row * 136 + c * 8 + e]) * wvo[c * 8 + e];
#pragma unroll
        for (int d = 1; d < 16; d <<= 1) s += __shfl_xor(s, d);
        if (c == 0) ug[i0 + row] = s + wvo[128];
    }

    // Phase B: q (w<4) | k (w>=4), 32 cols per wave, packed B
    floatx4 qacc[2][2];
#pragma unroll
    for (int mt = 0; mt < 2; ++mt)
#pragma unroll
        for (int nt = 0; nt < 2; ++nt) qacc[mt][nt] = (floatx4)0.0f;
    const unsigned short* wbp = (w < 4) ? wqp : wkp;
#pragma unroll
    for (int ks = 0; ks < 4; ++ks) {
        short8 a[2], b[2];
#pragma unroll
        for (int mt = 0; mt < 2; ++mt)
            a[mt] = *(const short8*)(hs + (mt * 16 + lr) * 136 + ks * 32 + lk * 8);
#pragma unroll
        for (int nt = 0; nt < 2; ++nt)
            b[nt] = *(const short8*)(wbp + ((((size_t)(wq4 * 2 + nt)) * 4 + ks) * 64 + lane) * 8);
#pragma unroll
        for (int mt = 0; mt < 2; ++mt)
#pragma unroll
            for (int nt = 0; nt < 2; ++nt)
                qacc[mt][nt] = MFMA16(a[mt], b[nt], qacc[mt][nt]);
    }
    const float* bb_ = (w < 4) ? bq : bk;
    unsigned short* dst = (w < 4) ? q : kt;
    const float sc = (w < 4) ? QSCALE : 1.0f;
#pragma unroll
    for (int mt = 0; mt < 2; ++mt)
#pragma unroll
        for (int nt = 0; nt < 2; ++nt) {
            int col = wq4 * 32 + nt * 16 + lr;
            float bb = bb_[col];
#pragma unroll
            for (int r = 0; r < 4; ++r)
                dst[(size_t)(i0 + mt * 16 + lk * 4 + r) * 128 + col] = f2bf((qacc[mt][nt][r] + bb) * sc);
        }
}

// ---------- K3: flash v6 — PV eliminated via u = V@W_out fold ----------
// grid (32, 32) x 256 thr; block = 256 q-rows, wave w owns m in [i0+w*64, +64).
// launch_bounds(256,1): ~150 VGPR needed — do NOT cap below (r6: cap 128 -> spill storm).
__global__ __launch_bounds__(256, 1) void k_flash(const unsigned short* __restrict__ qg,
                                                  const unsigned short* __restrict__ kg,
                                                  const float* __restrict__ ug,
                                                  float* __restrict__ os,
                                                  float* __restrict__ lp) {
    __shared__ __align__(16) unsigned short Ks[64 * 136];
    __shared__ __align__(16) float Us[64];
    const int tid = threadIdx.x;
    const int i0 = blockIdx.x * 256;
    const int w = tid >> 6, lane = tid & 63;
    const int lr = lane & 15, lk = lane >> 4;

    short8 qf[4][4];
#pragma unroll
    for (int mt = 0; mt < 4; ++mt)
#pragma unroll
        for (int ks = 0; ks < 4; ++ks)
            qf[mt][ks] = *(const short8*)(qg + (size_t)(i0 + w * 64 + mt * 16 + lr) * 128 + ks * 32 + lk * 8);

    float numv[4] = {0.f, 0.f, 0.f, 0.f};
    float lsum[4] = {0.f, 0.f, 0.f, 0.f};

    const int jbase = blockIdx.y * 256;
    const int krow = tid >> 2, kq = (tid & 3) << 5;

    short8 pk4[4];
    float4 pu;
    {
        const unsigned short* gk = kg + (size_t)(jbase + krow) * 128 + kq;
#pragma unroll
        for (int i = 0; i < 4; ++i) pk4[i] = *(const short8*)(gk + i * 8);
        if (tid < 16) pu = *(const float4*)(ug + jbase + tid * 4);
    }

    for (int jt = 0; jt < 4; ++jt) {
        __syncthreads();
        {
            unsigned short* dk = Ks + krow * 136 + kq;
#pragma unroll
            for (int i = 0; i < 4; ++i) *(short8*)(dk + i * 8) = pk4[i];
            if (tid < 16) *(float4*)(Us + tid * 4) = pu;
        }
        if (jt < 3) {
            int j0 = jbase + (jt + 1) * 64;
            const unsigned short* gk = kg + (size_t)(j0 + krow) * 128 + kq;
#pragma unroll
            for (int i = 0; i < 4; ++i) pk4[i] = *(const short8*)(gk + i * 8);
            if (tid < 16) pu = *(const float4*)(ug + j0 + tid * 4);
        }
        __syncthreads();

#pragma unroll
        for (int j4 = 0; j4 < 4; ++j4) {
            floatx4 sacc[4];
#pragma unroll
            for (int mt = 0; mt < 4; ++mt) sacc[mt] = (floatx4)0.0f;
#pragma unroll
            for (int ks = 0; ks < 4; ++ks) {
                short8 af = *(const short8*)(Ks + (j4 * 16 + lr) * 136 + ks * 32 + lk * 8);
#pragma unroll
                for (int mt = 0; mt < 4; ++mt)
                    sacc[mt] = MFMA16(af, qf[mt][ks], sacc[mt]);
            }
            floatx4 uu = *(const floatx4*)(Us + j4 * 16 + lk * 4);
#pragma unroll
            for (int mt = 0; mt < 4; ++mt) {
#pragma unroll
                for (int r = 0; r < 4; ++r) {
                    float p = __builtin_amdgcn_exp2f(sacc[mt][r]);
                    numv[mt] += p * uu[r];
                    lsum[mt] += p;
                }
            }
        }
    }

#pragma unroll
    for (int mt = 0; mt < 4; ++mt) {
        float n = numv[mt], l = lsum[mt];
        n += __shfl_xor(n, 16); n += __shfl_xor(n, 32);
        l += __shfl_xor(l, 16); l += __shfl_xor(l, 32);
        if (lk == 0) {
            size_t idx = (size_t)blockIdx.y * 8192 + i0 + w * 64 + mt * 16 + lr;
            os[idx] = n;
            lp[idx] = l;
        }
    }
}

// ---------- K4: out[row] = (sum_s num_s) / (sum_s l_s) + b_out ----------
__global__ __launch_bounds__(256) void k_out(const float* __restrict__ os,
                                             const float* __restrict__ lp,
                                             const float* __restrict__ bout,
                                             float* __restrict__ out) {
    int row = blockIdx.x * 256 + threadIdx.x;
    float o = 0.f, l = 0.f;
    for (int s = 0; s < NSPLIT; ++s) {
        o += os[(size_t)s * 8192 + row];
        l += lp[(size_t)s * 8192 + row];
    }
    out[row] = o / l + bout[0];
}

// ---------- launch ----------
extern "C" void kernel_launch(void* const* d_in, const int* in_sizes, int n_in,
                              void* d_out, int out_size, void* d_ws, size_t ws_size,
                              hipStream_t stream) {
    const float* x    = (const float*)d_in[0];
    const float* Wfc  = (const float*)d_in[1];
    const float* bfc  = (const float*)d_in[2];
    const float* Wg   = (const float*)d_in[3];
    const float* bg   = (const float*)d_in[4];
    const float* Wq   = (const float*)d_in[5];
    const float* bq   = (const float*)d_in[6];
    const float* Wk   = (const float*)d_in[7];
    const float* bk   = (const float*)d_in[8];
    const float* Wv   = (const float*)d_in[9];
    const float* bv   = (const float*)d_in[10];
    const float* Wout = (const float*)d_in[11];
    const float* bout = (const float*)d_in[12];
    char* ws = (char*)d_ws;

    unsigned short* qb   = (unsigned short*)(ws + Q_OFF);
    unsigned short* kb   = (unsigned short*)(ws + K_OFF);
    float*          ub   = (float*)(ws + U_OFF);
    unsigned short* wfcp = (unsigned short*)(ws + WFCT_OFF);
    unsigned short* wgp  = (unsigned short*)(ws + WGT_OFF);
    unsigned short* wqp  = (unsigned short*)(ws + WQT_OFF);
    unsigned short* wkp  = (unsigned short*)(ws + WKT_OFF);
    float*          wvo  = (float*)(ws + WVO_OFF);
    float* lpb = (float*)(ws + LP_OFF);
    float* osb = (float*)(ws + OS_OFF);

    k_prep<<<1217, 256, 0, stream>>>(Wfc, Wg, Wq, Wk, Wv, Wout, bv, wfcp, wgp, wqp, wkp, wvo);
    k_gq<<<256, 512, 0, stream>>>(x, wfcp, wgp, bfc, bg, wqp, wkp, bq, bk, wvo, qb, kb, ub);

    dim3 gf(32, NSPLIT);
    k_flash<<<gf, 256, 0, stream>>>(qb, kb, ub, osb, lpb);

    k_out<<<32, 256, 0, stream>>>(osb, lpb, bout, (float*)d_out);
}

// Round 9
// 136.078 us; speedup vs baseline: 2.6133x; 1.1040x over previous
//
#include <hip/hip_runtime.h>

// ---------- types ----------
typedef short short8 __attribute__((ext_vector_type(8)));        // 8 bf16 MFMA A/B frag
typedef float floatx4 __attribute__((ext_vector_type(4)));       // MFMA C/D frag

__device__ __forceinline__ unsigned short f2bf(float f) {
    unsigned u = __float_as_uint(f);
    u += 0x7fffu + ((u >> 16) & 1u);   // RNE
    return (unsigned short)(u >> 16);
}
__device__ __forceinline__ float bf2f(unsigned short b) {
    unsigned u = (unsigned)b << 16;
    return __uint_as_float(u);
}

#define MFMA16(a, b, c)  __builtin_amdgcn_mfma_f32_16x16x32_bf16((a), (b), (c), 0, 0, 0)

// ---------- ws layout (bytes) ----------
// q/k stored PACKED in MFMA-fragment order: element (row, d) lives at
//   ((rowtile*4 + ks)*64 + lane)*8 + e   where rowtile=row/16, lr=row%16,
//   ks=d/32, lk=(d%32)/8, e=d%8, lane=lk*16+lr.
// One wave frag load = one coalesced 1 KB transaction.
static constexpr size_t Q_OFF    = 0;                    // q*QSCALE packed bf16 2 MB
static constexpr size_t K_OFF    = 2u << 20;             // k packed bf16        2 MB
static constexpr size_t U_OFF    = 4u << 20;             // u fp32 [8192]       32 KB
static constexpr size_t WFCT_OFF = U_OFF + 32768;        // W_fc packed bf16   256 KB
static constexpr size_t WGT_OFF  = WFCT_OFF + 262144;    // W_gate packed bf16
static constexpr size_t WQT_OFF  = WGT_OFF + 262144;     // W_q packed bf16     32 KB
static constexpr size_t WKT_OFF  = WQT_OFF + 32768;      // W_k packed bf16
static constexpr size_t WVO_OFF  = WKT_OFF + 32768;      // wvo fp32 [128] + c0
static constexpr size_t LP_OFF   = 5u << 20;             // l partials fp32 [32][8192] 1 MB
static constexpr size_t OS_OFF   = 6u << 20;             // num partials fp32 [32][8192] 1 MB

static constexpr int NSPLIT = 32;
// log2(e)/sqrt(128): folded into stored q so P = exp2(S)
static constexpr float QSCALE = 0.1275174308f;

// ---------- K1: weights -> MFMA-packed bf16 + wvo = W_v @ W_out GEMV ----------
__global__ void k_prep(const float* __restrict__ wfc, const float* __restrict__ wg,
                       const float* __restrict__ wq, const float* __restrict__ wk,
                       const float* __restrict__ wv, const float* __restrict__ wout,
                       const float* __restrict__ bv,
                       unsigned short* __restrict__ dfc, unsigned short* __restrict__ dg,
                       unsigned short* __restrict__ dq, unsigned short* __restrict__ dk,
                       float* __restrict__ wvo) {
    if (blockIdx.x == 1216) {
        int t = threadIdx.x;
        if (t < 128) {
            float s = 0.f;
            for (int j = 0; j < 128; ++j) s += wv[t * 128 + j] * wout[j];
            wvo[t] = s;
        } else if (t == 128) {
            float s = 0.f;
            for (int j = 0; j < 128; ++j) s += bv[j] * wout[j];
            wvo[128] = s;   // c0
        }
        return;
    }
    int i = blockIdx.x * 256 + threadIdx.x;
    const float* s; unsigned short* d; int base, nchunk;
    if (i < 131072)      { s = wfc; d = dfc; nchunk = 32; base = 0; }
    else if (i < 262144) { s = wg;  d = dg;  nchunk = 32; base = 131072; }
    else if (i < 278528) { s = wq;  d = dq;  nchunk = 4;  base = 262144; }
    else if (i < 294912) { s = wk;  d = dk;  nchunk = 4;  base = 278528; }
    else return;
    int j = i - base;
    int kk = j >> 7, nn = j & 127;        // source W[kk][nn], row-major K x 128
    int t = nn >> 4, lr = nn & 15;
    int c = kk >> 5, lk = (kk >> 3) & 3, e = kk & 7;
    d[(((t * nchunk + c) * 64) + lr + 16 * lk) * 8 + e] = f2bf(s[j]);
}

// ---------- K2: fused gated-linear + QK + u (packed-B, packed q/k outputs) ----------
// grid 256 x 512 thr; block = 32 rows, 8 waves.
__global__ __launch_bounds__(512) void k_gq(const float* __restrict__ x,
                                            const unsigned short* __restrict__ wfcp,
                                            const unsigned short* __restrict__ wgp,
                                            const float* __restrict__ bfc,
                                            const float* __restrict__ bg,
                                            const unsigned short* __restrict__ wqp,
                                            const unsigned short* __restrict__ wkp,
                                            const float* __restrict__ bq,
                                            const float* __restrict__ bk,
                                            const float* __restrict__ wvo,
                                            unsigned short* __restrict__ qpk,
                                            unsigned short* __restrict__ kpk,
                                            float* __restrict__ ug) {
    __shared__ __align__(16) unsigned short xs[2][32 * 136];
    __shared__ __align__(16) float gbuf[32 * 132];
    __shared__ __align__(16) unsigned short hs[32 * 136];
    const int tid = threadIdx.x;
    const int i0 = blockIdx.x * 32;
    const int w = tid >> 6, lane = tid & 63;
    const int lr = lane & 15, lk = lane >> 4;

    const int isg = (w >= 4);
    const int wq4 = w & 3;                 // 0..3: which 32-col group
    const unsigned short* wp = isg ? wgp : wfcp;

    floatx4 acc[2][2];
#pragma unroll
    for (int mt = 0; mt < 2; ++mt)
#pragma unroll
        for (int nt = 0; nt < 2; ++nt) acc[mt][nt] = (floatx4)0.0f;

    const int srow = tid >> 4, se = tid & 15;   // 32 rows x 16 thr, 8 floats each
    const float* gp0 = x + (size_t)(i0 + srow) * 1024 + se * 8;
    float4 ra = *(const float4*)gp0;
    float4 rb = *(const float4*)(gp0 + 4);

    for (int kc = 0; kc < 8; ++kc) {
        {   // commit prefetched chunk to LDS buf kc&1 (fp32 -> bf16)
            short8 t;
            unsigned short* tp = (unsigned short*)&t;
            tp[0] = f2bf(ra.x); tp[1] = f2bf(ra.y); tp[2] = f2bf(ra.z); tp[3] = f2bf(ra.w);
            tp[4] = f2bf(rb.x); tp[5] = f2bf(rb.y); tp[6] = f2bf(rb.z); tp[7] = f2bf(rb.w);
            *(short8*)(xs[kc & 1] + srow * 136 + se * 8) = t;
        }
        if (kc < 7) {
            const float* gp = gp0 + (kc + 1) * 128;
            ra = *(const float4*)gp;
            rb = *(const float4*)(gp + 4);
        }
        __syncthreads();
        const unsigned short* xb = xs[kc & 1];
#pragma unroll
        for (int ks = 0; ks < 4; ++ks) {
            const int c = kc * 4 + ks;
            short8 a[2], b[2];
#pragma unroll
            for (int mt = 0; mt < 2; ++mt)
                a[mt] = *(const short8*)(xb + (mt * 16 + lr) * 136 + ks * 32 + lk * 8);
#pragma unroll
            for (int nt = 0; nt < 2; ++nt)
                b[nt] = *(const short8*)(wp + ((((size_t)(wq4 * 2 + nt)) * 32 + c) * 64 + lane) * 8);
#pragma unroll
            for (int mt = 0; mt < 2; ++mt)
#pragma unroll
                for (int nt = 0; nt < 2; ++nt)
                    acc[mt][nt] = MFMA16(a[mt], b[nt], acc[mt][nt]);
        }
    }
    __syncthreads();
    // epilogue A: gate waves write sigmoid; fc waves combine -> h
    if (isg) {
#pragma unroll
        for (int mt = 0; mt < 2; ++mt)
#pragma unroll
            for (int nt = 0; nt < 2; ++nt) {
                int col = wq4 * 32 + nt * 16 + lr;
                float bb = bg[col];
#pragma unroll
                for (int r = 0; r < 4; ++r) {
                    float v = acc[mt][nt][r] + bb;
                    gbuf[(mt * 16 + lk * 4 + r) * 132 + col] =
                        __builtin_amdgcn_rcpf(1.0f + __builtin_amdgcn_exp2f(-1.4426950408889634f * v));
                }
            }
    }
    __syncthreads();
    if (!isg) {
#pragma unroll
        for (int mt = 0; mt < 2; ++mt)
#pragma unroll
            for (int nt = 0; nt < 2; ++nt) {
                int col = wq4 * 32 + nt * 16 + lr;
                float bb = bfc[col];
#pragma unroll
                for (int r = 0; r < 4; ++r) {
                    int row = mt * 16 + lk * 4 + r;
                    hs[row * 136 + col] = f2bf((acc[mt][nt][r] + bb) * gbuf[row * 132 + col]);
                }
            }
    }
    __syncthreads();

    // u[i] = h[i] @ wvo + c0 : thread t -> row t>>4, 8-elem chunk (t&15)*8
    {
        int row = tid >> 4, c = tid & 15;
        float s = 0.f;
#pragma unroll
        for (int e = 0; e < 8; ++e)
            s += bf2f(hs[row * 136 + c * 8 + e]) * wvo[c * 8 + e];
#pragma unroll
        for (int d = 1; d < 16; d <<= 1) s += __shfl_xor(s, d);
        if (c == 0) ug[i0 + row] = s + wvo[128];
    }

    // Phase B: q (w<4) | k (w>=4), 32 cols per wave, packed B
    floatx4 qacc[2][2];
#pragma unroll
    for (int mt = 0; mt < 2; ++mt)
#pragma unroll
        for (int nt = 0; nt < 2; ++nt) qacc[mt][nt] = (floatx4)0.0f;
    const unsigned short* wbp = (w < 4) ? wqp : wkp;
#pragma unroll
    for (int ks = 0; ks < 4; ++ks) {
        short8 a[2], b[2];
#pragma unroll
        for (int mt = 0; mt < 2; ++mt)
            a[mt] = *(const short8*)(hs + (mt * 16 + lr) * 136 + ks * 32 + lk * 8);
#pragma unroll
        for (int nt = 0; nt < 2; ++nt)
            b[nt] = *(const short8*)(wbp + ((((size_t)(wq4 * 2 + nt)) * 4 + ks) * 64 + lane) * 8);
#pragma unroll
        for (int mt = 0; mt < 2; ++mt)
#pragma unroll
            for (int nt = 0; nt < 2; ++nt)
                qacc[mt][nt] = MFMA16(a[mt], b[nt], qacc[mt][nt]);
    }
    // epilogue B: bias+scale -> LDS tile (xs reused: [0]=q, [1]=k)
    {
        unsigned short* dstl = xs[isg];
        const float* bb_ = (w < 4) ? bq : bk;
        const float sc = (w < 4) ? QSCALE : 1.0f;
#pragma unroll
        for (int mt = 0; mt < 2; ++mt)
#pragma unroll
            for (int nt = 0; nt < 2; ++nt) {
                int col = wq4 * 32 + nt * 16 + lr;
                float bb = bb_[col];
#pragma unroll
                for (int r = 0; r < 4; ++r)
                    dstl[(mt * 16 + lk * 4 + r) * 136 + col] = f2bf((qacc[mt][nt][r] + bb) * sc);
            }
    }
    __syncthreads();
    // cooperative packed store: 16 segments (sel,rtl,ks), wave w -> sel=w>>2, 2 ks each
    {
        int sel = w >> 2, p = w & 3;
        int rtl = p >> 1, ks2 = (p & 1) * 2;
        unsigned short* gdst = sel ? kpk : qpk;
        const unsigned short* src = xs[sel];
        size_t rt = (i0 >> 4) + rtl;
#pragma unroll
        for (int s = 0; s < 2; ++s) {
            int ks = ks2 + s;
            short8 v = *(const short8*)(src + (rtl * 16 + lr) * 136 + ks * 32 + lk * 8);
            *(short8*)(gdst + ((rt * 4 + ks) * 64 + lane) * 8) = v;
        }
    }
}

// ---------- K3: flash v7 — LDS-free, barrier-free, packed frags ----------
// grid (32, 32) x 256 thr; block = 256 q-rows, wave w owns rows w*64..+64 (4 row-tiles).
// Per 16-row j sub-tile: 4 coalesced K-frag loads (prefetched 1 ahead) + u float4;
// 16 MFMA (S^T = K@Q^T) + exp2/fma/add. No LDS, no __syncthreads.
// launch_bounds(256,1): ~145 VGPR — do NOT cap below (r6: cap 128 -> spill storm).
__global__ __launch_bounds__(256, 1) void k_flash(const unsigned short* __restrict__ qp,
                                                  const unsigned short* __restrict__ kp,
                                                  const float* __restrict__ ug,
                                                  float* __restrict__ os,
                                                  float* __restrict__ lp) {
    const int tid = threadIdx.x;
    const int w = tid >> 6, lane = tid & 63;
    const int lr = lane & 15, lk = lane >> 4;
    const int rt0 = blockIdx.x * 16 + w * 4;    // q row-tile base

    // Q frags: 16 coalesced 1KB loads, live in registers
    short8 qf[4][4];
#pragma unroll
    for (int mt = 0; mt < 4; ++mt)
#pragma unroll
        for (int ks = 0; ks < 4; ++ks)
            qf[mt][ks] = *(const short8*)(qp + (((size_t)(rt0 + mt) * 4 + ks) * 64 + lane) * 8);

    float numv[4] = {0.f, 0.f, 0.f, 0.f};
    float lsum[4] = {0.f, 0.f, 0.f, 0.f};

    const int jt0 = blockIdx.y * 16;            // 16 j row-tiles per split

    short8 af[4], afn[4];
    floatx4 uu, uun;
#pragma unroll
    for (int ks = 0; ks < 4; ++ks)
        af[ks] = *(const short8*)(kp + (((size_t)jt0 * 4 + ks) * 64 + lane) * 8);
    uu = *(const floatx4*)(ug + jt0 * 16 + lk * 4);

    for (int t = 0; t < 16; ++t) {
        if (t < 15) {   // prefetch next sub-tile (stays in flight across the MFMAs)
#pragma unroll
            for (int ks = 0; ks < 4; ++ks)
                afn[ks] = *(const short8*)(kp + (((size_t)(jt0 + t + 1) * 4 + ks) * 64 + lane) * 8);
            uun = *(const floatx4*)(ug + (jt0 + t + 1) * 16 + lk * 4);
        }
        floatx4 sacc[4];
#pragma unroll
        for (int mt = 0; mt < 4; ++mt) sacc[mt] = (floatx4)0.0f;
#pragma unroll
        for (int ks = 0; ks < 4; ++ks)
#pragma unroll
            for (int mt = 0; mt < 4; ++mt)
                sacc[mt] = MFMA16(af[ks], qf[mt][ks], sacc[mt]);
        // p = exp2(s); num += p*u; l += p   (lane: j = (jt0+t)*16 + lk*4 + r, m = rows rt0..+4 *16 + lr)
#pragma unroll
        for (int mt = 0; mt < 4; ++mt) {
#pragma unroll
            for (int r = 0; r < 4; ++r) {
                float p = __builtin_amdgcn_exp2f(sacc[mt][r]);
                numv[mt] += p * uu[r];
                lsum[mt] += p;
            }
        }
#pragma unroll
        for (int ks = 0; ks < 4; ++ks) af[ks] = afn[ks];
        uu = uun;
    }

    // reduce over lk (lane bits 4,5) and store per-split partials
#pragma unroll
    for (int mt = 0; mt < 4; ++mt) {
        float n = numv[mt], l = lsum[mt];
        n += __shfl_xor(n, 16); n += __shfl_xor(n, 32);
        l += __shfl_xor(l, 16); l += __shfl_xor(l, 32);
        if (lk == 0) {
            size_t idx = (size_t)blockIdx.y * 8192 + (size_t)(rt0 + mt) * 16 + lr;
            os[idx] = n;
            lp[idx] = l;
        }
    }
}

// ---------- K4: out[row] = (sum_s num_s) / (sum_s l_s) + b_out ----------
__global__ __launch_bounds__(256) void k_out(const float* __restrict__ os,
                                             const float* __restrict__ lp,
                                             const float* __restrict__ bout,
                                             float* __restrict__ out) {
    int row = blockIdx.x * 256 + threadIdx.x;
    float o = 0.f, l = 0.f;
    for (int s = 0; s < NSPLIT; ++s) {
        o += os[(size_t)s * 8192 + row];
        l += lp[(size_t)s * 8192 + row];
    }
    out[row] = o / l + bout[0];
}

// ---------- launch ----------
extern "C" void kernel_launch(void* const* d_in, const int* in_sizes, int n_in,
                              void* d_out, int out_size, void* d_ws, size_t ws_size,
                              hipStream_t stream) {
    const float* x    = (const float*)d_in[0];
    const float* Wfc  = (const float*)d_in[1];
    const float* bfc  = (const float*)d_in[2];
    const float* Wg   = (const float*)d_in[3];
    const float* bg   = (const float*)d_in[4];
    const float* Wq   = (const float*)d_in[5];
    const float* bq   = (const float*)d_in[6];
    const float* Wk   = (const float*)d_in[7];
    const float* bk   = (const float*)d_in[8];
    const float* Wv   = (const float*)d_in[9];
    const float* bv   = (const float*)d_in[10];
    const float* Wout = (const float*)d_in[11];
    const float* bout = (const float*)d_in[12];
    char* ws = (char*)d_ws;

    unsigned short* qb   = (unsigned short*)(ws + Q_OFF);
    unsigned short* kb   = (unsigned short*)(ws + K_OFF);
    float*          ub   = (float*)(ws + U_OFF);
    unsigned short* wfcp = (unsigned short*)(ws + WFCT_OFF);
    unsigned short* wgp  = (unsigned short*)(ws + WGT_OFF);
    unsigned short* wqp  = (unsigned short*)(ws + WQT_OFF);
    unsigned short* wkp  = (unsigned short*)(ws + WKT_OFF);
    float*          wvo  = (float*)(ws + WVO_OFF);
    float* lpb = (float*)(ws + LP_OFF);
    float* osb = (float*)(ws + OS_OFF);

    k_prep<<<1217, 256, 0, stream>>>(Wfc, Wg, Wq, Wk, Wv, Wout, bv, wfcp, wgp, wqp, wkp, wvo);
    k_gq<<<256, 512, 0, stream>>>(x, wfcp, wgp, bfc, bg, wqp, wkp, bq, bk, wvo, qb, kb, ub);

    dim3 gf(32, NSPLIT);
    k_flash<<<gf, 256, 0, stream>>>(qb, kb, ub, osb, lpb);

    k_out<<<32, 256, 0, stream>>>(osb, lpb, bout, (float*)d_out);
}